// Round 10
// baseline (550.945 us; speedup 1.0000x reference)
//
#include <hip/hip_runtime.h>
#include <stdint.h>

#define N_TOK 8192
#define C_DIM 1024
#define H_DIM 3072
#define N_EXP 8
#define N_ASSIGN (N_TOK * 2)

typedef __attribute__((ext_vector_type(8))) short short8;
typedef __attribute__((ext_vector_type(4))) float f32x4;

__device__ __forceinline__ unsigned short f2bf(float f) {
    union { float f; uint32_t u; } v; v.f = f;
    uint32_t r = (v.u + 0x7FFFu + ((v.u >> 16) & 1u)) >> 16;
    return (unsigned short)r;
}

#define GLDS16(SRC, DST) __builtin_amdgcn_global_load_lds( \
    (const __attribute__((address_space(1))) void*)(SRC),  \
    (__attribute__((address_space(3))) void*)(DST), 16, 0, 0)

#define SBAR() do { __builtin_amdgcn_sched_barrier(0); \
    __builtin_amdgcn_s_barrier();                      \
    __builtin_amdgcn_sched_barrier(0); } while (0)

#define WAITASM(S) do { __builtin_amdgcn_sched_barrier(0); \
    asm volatile(S ::: "memory");                          \
    __builtin_amdgcn_sched_barrier(0); } while (0)

// ---------------- transpose + fp32->bf16: out[col][row] = in[row][col], per expert (grid.z)
__global__ __launch_bounds__(256) void transpose_bf16_kernel(const float* __restrict__ in,
                                                             unsigned short* __restrict__ out,
                                                             int rows, int cols) {
    __shared__ float tile[64][65];
    int e = blockIdx.z;
    const float* ip = in + (size_t)e * rows * cols;
    unsigned short* op = out + (size_t)e * rows * cols;
    int c0 = blockIdx.x * 64;
    int r0 = blockIdx.y * 64;
    int t = threadIdx.x;
    int lr = t >> 4, lc4 = t & 15;
#pragma unroll
    for (int it = 0; it < 4; it++) {
        int r = lr + it * 16;
        float4 v = *(const float4*)&ip[(size_t)(r0 + r) * cols + c0 + lc4 * 4];
        tile[lc4 * 4 + 0][r] = v.x;
        tile[lc4 * 4 + 1][r] = v.y;
        tile[lc4 * 4 + 2][r] = v.z;
        tile[lc4 * 4 + 3][r] = v.w;
    }
    __syncthreads();
#pragma unroll
    for (int it = 0; it < 4; it++) {
        int oc = lr + it * 16;
        ushort4 o;
        o.x = f2bf(tile[oc][lc4 * 4 + 0]);
        o.y = f2bf(tile[oc][lc4 * 4 + 1]);
        o.z = f2bf(tile[oc][lc4 * 4 + 2]);
        o.w = f2bf(tile[oc][lc4 * 4 + 3]);
        *(ushort4*)&op[(size_t)(c0 + oc) * rows + r0 + lc4 * 4] = o;
    }
}

// ---------------- router
__global__ __launch_bounds__(256) void router_kernel(const float* __restrict__ x, const float* __restrict__ Wr,
                                                     int2* __restrict__ idx2, float2* __restrict__ wgt2,
                                                     float* __restrict__ piAcc, int* __restrict__ cntAcc) {
    __shared__ float s_pi[8];
    __shared__ int s_cnt[8];
    int t = threadIdx.x;
    if (t < 8) { s_pi[t] = 0.f; s_cnt[t] = 0; }
    __syncthreads();
    int lane = t & 63;
    int wid = t >> 6;
    int gwv = blockIdx.x * 4 + wid;
    int nw = gridDim.x * 4;
    for (int n = gwv; n < N_TOK; n += nw) {
        float acc[8];
#pragma unroll
        for (int e = 0; e < 8; e++) acc[e] = 0.f;
        const float* xr = x + (size_t)n * C_DIM;
#pragma unroll
        for (int j = 0; j < 16; j++) {
            int k = lane + 64 * j;
            float xv = xr[k];
            const float4* wr4 = (const float4*)(Wr + (size_t)k * 8);
            float4 a = wr4[0], b = wr4[1];
            acc[0] += xv * a.x; acc[1] += xv * a.y; acc[2] += xv * a.z; acc[3] += xv * a.w;
            acc[4] += xv * b.x; acc[5] += xv * b.y; acc[6] += xv * b.z; acc[7] += xv * b.w;
        }
#pragma unroll
        for (int off = 1; off < 64; off <<= 1) {
#pragma unroll
            for (int e = 0; e < 8; e++) acc[e] += __shfl_xor(acc[e], off, 64);
        }
        float m = acc[0];
#pragma unroll
        for (int e = 1; e < 8; e++) m = fmaxf(m, acc[e]);
        float p[8]; float s = 0.f;
#pragma unroll
        for (int e = 0; e < 8; e++) { p[e] = __expf(acc[e] - m); s += p[e]; }
        float inv = 1.f / s;
#pragma unroll
        for (int e = 0; e < 8; e++) p[e] *= inv;
        int i0 = 0; float l0 = acc[0];
#pragma unroll
        for (int e = 1; e < 8; e++) if (acc[e] > l0) { l0 = acc[e]; i0 = e; }
        int i1 = -1; float l1 = -1e30f;
#pragma unroll
        for (int e = 0; e < 8; e++) if (e != i0 && acc[e] > l1) { l1 = acc[e]; i1 = e; }
        if (lane == 0) {
            float v0 = p[i0], v1 = p[i1];
            float rs = 1.f / (v0 + v1);
            idx2[n] = make_int2(i0, i1);
            wgt2[n] = make_float2(v0 * rs, v1 * rs);
            atomicAdd(&s_cnt[i0], 1);
            atomicAdd(&s_cnt[i1], 1);
#pragma unroll
            for (int e = 0; e < 8; e++) atomicAdd(&s_pi[e], p[e]);
        }
    }
    __syncthreads();
    if (t < 8) { atomicAdd(&piAcc[t], s_pi[t]); atomicAdd(&cntAcc[t], s_cnt[t]); }
}

// ---------------- offsets + aux loss
__global__ void finalize_router_kernel(const int* __restrict__ cnt, const float* __restrict__ pi,
                                       int* __restrict__ off, float* __restrict__ aux_out) {
    if (threadIdx.x == 0) {
        int o = 0;
        float dot = 0.f;
        for (int e = 0; e < 8; e++) {
            off[e] = o;
            o += cnt[e];
            dot += (float)cnt[e] * pi[e];
        }
        aux_out[0] = 0.01f * 8.f * dot / ((float)N_TOK * (float)N_TOK);
    }
}

// ---------------- scatter
__global__ __launch_bounds__(256) void scatter_kernel(const int2* __restrict__ idx2, const float2* __restrict__ wgt2,
                                                      const int* __restrict__ off, int* __restrict__ cursor,
                                                      int* __restrict__ tok, float* __restrict__ gwArr) {
    __shared__ int lcnt[8], lbase[8];
    int t = threadIdx.x;
    if (t < 8) lcnt[t] = 0;
    __syncthreads();
    int a = blockIdx.x * 256 + t;
    int n = a >> 1, k = a & 1;
    int2 id = idx2[n];
    float2 w = wgt2[n];
    int e = k ? id.y : id.x;
    float wv = k ? w.y : w.x;
    int rank = atomicAdd(&lcnt[e], 1);
    __syncthreads();
    if (t < 8) lbase[t] = atomicAdd(&cursor[t], lcnt[t]);
    __syncthreads();
    int pos = off[e] + lbase[e] + rank;
    tok[pos] = n;
    gwArr[pos] = wv;
}

// ---------------- gather
__global__ __launch_bounds__(256) void gather_kernel(const float* __restrict__ x, const int* __restrict__ tok,
                                                     unsigned short* __restrict__ xg) {
    int wid = threadIdx.x >> 6, lane = threadIdx.x & 63;
    int row = blockIdx.x * 4 + wid;
    int n = tok[row];
    const float4* src = (const float4*)(x + (size_t)n * C_DIM);
    ushort4* dst = (ushort4*)(xg + (size_t)row * C_DIM);
#pragma unroll
    for (int j = 0; j < 4; j++) {
        float4 v = src[lane + 64 * j];
        ushort4 o;
        o.x = f2bf(v.x); o.y = f2bf(v.y); o.z = f2bf(v.z); o.w = f2bf(v.w);
        dst[lane + 64 * j] = o;
    }
}

// ---------------- grouped GEMM, m201-style 4-phase schedule on BM=256 x BN=128, BK=64,
// 8 waves (2M x 4N; per-wave C = 128x32, acc[8][2] -> 64 AGPR), 3 full LDS buffers
// (3 x 48 KiB = 144 KiB), stage-lead = 2 tiles, NEVER-DRAIN:
//  tile t, phases (2 barriers each, lgkmcnt(0) seals reads before closing barrier):
//   ph1: stage 2xA(t+2) ; vmcnt(8) ; BAR ; ds_read a0-3,b0-1 (kk0) ; lgkm0 ; 8 MFMA ; BAR
//   ph2: stage 2xA(t+2) ; ds_read a4-7 (kk0)        ; BAR ; lgkm0 ; 8 MFMA ; BAR
//   ph3: stage 1xB(t+2) ; ds_read a0-3,b0-1 (kk1)   ; BAR ; lgkm0 ; 8 MFMA ; BAR
//   ph4: stage 1xB(t+2) ; ds_read a4-7 (kk1)        ; BAR ; lgkm0 ; 8 MFMA ; BAR
// FIFO audit: 6 loads/thread/tile (A0..A3,B0,B1). At ph1(t): outstanding =
// t+1's 6 + t+2's 2 = 8 newest -> vmcnt(8) forces tile t landed. Tail: t==nt-2 ->
// vmcnt(6); t==nt-1 -> vmcnt(0). Overwrite audit: t+2 targets buf (t+2)%3 whose
// old content (t-1) was last read at t-1 ph4, sealed by lgkm0 + >=2 barriers
// before this stage issue. vmcnt+BAR at ph1 makes all-waves' tile-t loads visible.
// LDS rows = 64 shorts = 128 B; within-row chunk swizzle c ^= (row&7) on SOURCE
// and READ (contiguous 8-row staging, 0-conflict reads; proven R7).
// Work: flat (e, mblk, y, s) + bijective XCD remap (m204), mb-inner.
// EPI=0: hs = bf16(silu(acc)); EPI=1: atomicAdd(out[tok*C+c], gw*acc)
template <int EPI>
__global__ __launch_bounds__(512) void moe_gemm_kernel(
    const unsigned short* __restrict__ A, int ldA,
    const unsigned short* __restrict__ Bt, int ldB, int bRowOff, int bColOff,
    int Kseg, int NY, int SK,
    const int* __restrict__ cnt, const int* __restrict__ off,
    const int* __restrict__ tok, const float* __restrict__ gwArr,
    unsigned short* __restrict__ hs, int ldH,
    float* __restrict__ out) {
    __shared__ unsigned short smem[73728];   // 3 bufs x (A 16384 + B 8192 shorts) = 144 KiB

    // ---- flat work total + bijective XCD remap
    int nbs[8];
    int tot = 0;
#pragma unroll
    for (int i = 0; i < 8; i++) {
        nbs[i] = (cnt[i] + 255) >> 8;
        tot += nbs[i] * NY * SK;
    }
    int p = blockIdx.x;
    int q = tot >> 3, r = tot & 7;
    int xx = p & 7, sp = p >> 3;
    int capx = (xx < r) ? q + 1 : q;
    if (sp >= capx) return;
    int wi = (xx < r) ? xx * (q + 1) + sp : r * (q + 1) + (xx - r) * q + sp;

    // ---- decode wi -> (e, mblk, y, s); mb-inner for B-stripe L2 reuse
    int base = 0, e = -1, enb = 0, local = 0;
#pragma unroll
    for (int i = 0; i < 8; i++) {
        int sz = nbs[i] * NY * SK;
        if (e < 0 && wi < base + sz) { e = i; enb = nbs[i]; local = wi - base; }
        base += sz;
    }
    if (e < 0) return;
    int ys = local / enb;
    int mblk = local - ys * enb;
    int s = ys / NY;
    int y = ys - s * NY;
    int M = cnt[e];
    int m0 = mblk * 256;
    int baseRow = off[e];
    int n0 = y * 128;
    int acol = s * Kseg;
    int bcol = bColOff + s * Kseg;

    int tid = threadIdx.x;
    int lane = tid & 63;
    int wid = tid >> 6;
    int wr = wid >> 2;            // 2 wave-rows of 128
    int wc = wid & 3;             // 4 wave-cols of 32

    f32x4 acc[8][2];
#pragma unroll
    for (int i = 0; i < 8; i++)
#pragma unroll
        for (int j = 0; j < 2; j++) acc[i][j] = (f32x4)0.f;

    const unsigned short* Bex = Bt + (size_t)e * (size_t)(C_DIM * H_DIM);

    // ---- staging descriptors. A: 256 rows x 8 chunks = 2048 -> 4/thread.
    // B: 128 rows x 8 chunks = 1024 -> 2/thread. chunk c: row=c>>3, pos=c&7,
    // src chunk = pos ^ (row&7); contiguous 8-row (1 KiB) wave instructions.
    const unsigned short* srcA[4];
    const unsigned short* srcB[2];
    int ldsA[4], ldsB[2];
#pragma unroll
    for (int i = 0; i < 4; i++) {
        int c = i * 512 + tid;
        int row = c >> 3;
        int sc = (c & 7) ^ (row & 7);
        int rg = m0 + row; if (rg > M - 1) rg = M - 1;
        srcA[i] = A + (size_t)(baseRow + rg) * ldA + acol + sc * 8;
        ldsA[i] = (c & ~63) * 8;
    }
#pragma unroll
    for (int i = 0; i < 2; i++) {
        int c = i * 512 + tid;
        int row = c >> 3;
        int sc = (c & 7) ^ (row & 7);
        srcB[i] = Bex + (size_t)(bRowOff + n0 + row) * ldB + bcol + sc * 8;
        ldsB[i] = 16384 + (c & ~63) * 8;
    }

    // ---- swizzled read offsets (shorts in buffer)
    int kq = lane >> 4;
    int rsub = lane & 15;
    int offA[2][8], offB[2][2];
#pragma unroll
    for (int kk = 0; kk < 2; kk++) {
#pragma unroll
        for (int m = 0; m < 8; m++) {
            int row = wr * 128 + m * 16 + rsub;
            offA[kk][m] = row * 64 + (((kk * 4 + kq) ^ (row & 7)) * 8);
        }
#pragma unroll
        for (int n = 0; n < 2; n++) {
            int col = wc * 32 + n * 16 + rsub;
            offB[kk][n] = 16384 + col * 64 + (((kk * 4 + kq) ^ (col & 7)) * 8);
        }
    }

    int nt = Kseg >> 6;
    // ---- prologue: stage tiles 0 and 1 fully (6 loads each)
#pragma unroll
    for (int tt = 0; tt < 2; tt++) {
        int bb = tt * 24576;
#pragma unroll
        for (int i = 0; i < 4; i++) { GLDS16(srcA[i], &smem[bb + ldsA[i]]); srcA[i] += 64; }
#pragma unroll
        for (int i = 0; i < 2; i++) { GLDS16(srcB[i], &smem[bb + ldsB[i]]); srcB[i] += 64; }
    }

    int bufR = 0, bufW = 2 * 24576;
#pragma unroll 1
    for (int t = 0; t < nt; ++t) {
        const unsigned short* bp = &smem[bufR];
        bool ds = (t + 2 < nt);
        short8 a0, a1, a2, a3, b0, b1;
        // ---------- ph1: stage A0,A1(t+2); vmcnt; BAR; read kk0 mq0 + b kk0; MFMA
        if (ds) {
            GLDS16(srcA[0], &smem[bufW + ldsA[0]]); srcA[0] += 64;
            GLDS16(srcA[1], &smem[bufW + ldsA[1]]); srcA[1] += 64;
        }
        if (t < nt - 2)       WAITASM("s_waitcnt vmcnt(8)");
        else if (t == nt - 2) WAITASM("s_waitcnt vmcnt(6)");
        else                  WAITASM("s_waitcnt vmcnt(0)");
        SBAR();
        a0 = *(const short8*)&bp[offA[0][0]];
        a1 = *(const short8*)&bp[offA[0][1]];
        a2 = *(const short8*)&bp[offA[0][2]];
        a3 = *(const short8*)&bp[offA[0][3]];
        b0 = *(const short8*)&bp[offB[0][0]];
        b1 = *(const short8*)&bp[offB[0][1]];
        WAITASM("s_waitcnt lgkmcnt(0)");
        __builtin_amdgcn_s_setprio(1);
        acc[0][0] = __builtin_amdgcn_mfma_f32_16x16x32_bf16(a0, b0, acc[0][0], 0, 0, 0);
        acc[0][1] = __builtin_amdgcn_mfma_f32_16x16x32_bf16(a0, b1, acc[0][1], 0, 0, 0);
        acc[1][0] = __builtin_amdgcn_mfma_f32_16x16x32_bf16(a1, b0, acc[1][0], 0, 0, 0);
        acc[1][1] = __builtin_amdgcn_mfma_f32_16x16x32_bf16(a1, b1, acc[1][1], 0, 0, 0);
        acc[2][0] = __builtin_amdgcn_mfma_f32_16x16x32_bf16(a2, b0, acc[2][0], 0, 0, 0);
        acc[2][1] = __builtin_amdgcn_mfma_f32_16x16x32_bf16(a2, b1, acc[2][1], 0, 0, 0);
        acc[3][0] = __builtin_amdgcn_mfma_f32_16x16x32_bf16(a3, b0, acc[3][0], 0, 0, 0);
        acc[3][1] = __builtin_amdgcn_mfma_f32_16x16x32_bf16(a3, b1, acc[3][1], 0, 0, 0);
        __builtin_amdgcn_s_setprio(0);
        SBAR();
        // ---------- ph2: stage A2,A3(t+2); read kk0 mq1; MFMA
        if (ds) {
            GLDS16(srcA[2], &smem[bufW + ldsA[2]]); srcA[2] += 64;
            GLDS16(srcA[3], &smem[bufW + ldsA[3]]); srcA[3] += 64;
        }
        a0 = *(const short8*)&bp[offA[0][4]];
        a1 = *(const short8*)&bp[offA[0][5]];
        a2 = *(const short8*)&bp[offA[0][6]];
        a3 = *(const short8*)&bp[offA[0][7]];
        SBAR();
        WAITASM("s_waitcnt lgkmcnt(0)");
        __builtin_amdgcn_s_setprio(1);
        acc[4][0] = __builtin_amdgcn_mfma_f32_16x16x32_bf16(a0, b0, acc[4][0], 0, 0, 0);
        acc[4][1] = __builtin_amdgcn_mfma_f32_16x16x32_bf16(a0, b1, acc[4][1], 0, 0, 0);
        acc[5][0] = __builtin_amdgcn_mfma_f32_16x16x32_bf16(a1, b0, acc[5][0], 0, 0, 0);
        acc[5][1] = __builtin_amdgcn_mfma_f32_16x16x32_bf16(a1, b1, acc[5][1], 0, 0, 0);
        acc[6][0] = __builtin_amdgcn_mfma_f32_16x16x32_bf16(a2, b0, acc[6][0], 0, 0, 0);
        acc[6][1] = __builtin_amdgcn_mfma_f32_16x16x32_bf16(a2, b1, acc[6][1], 0, 0, 0);
        acc[7][0] = __builtin_amdgcn_mfma_f32_16x16x32_bf16(a3, b0, acc[7][0], 0, 0, 0);
        acc[7][1] = __builtin_amdgcn_mfma_f32_16x16x32_bf16(a3, b1, acc[7][1], 0, 0, 0);
        __builtin_amdgcn_s_setprio(0);
        SBAR();
        // ---------- ph3: stage B0(t+2); read kk1 mq0 + b kk1; MFMA
        if (ds) { GLDS16(srcB[0], &smem[bufW + ldsB[0]]); srcB[0] += 64; }
        a0 = *(const short8*)&bp[offA[1][0]];
        a1 = *(const short8*)&bp[offA[1][1]];
        a2 = *(const short8*)&bp[offA[1][2]];
        a3 = *(const short8*)&bp[offA[1][3]];
        b0 = *(const short8*)&bp[offB[1][0]];
        b1 = *(const short8*)&bp[offB[1][1]];
        SBAR();
        WAITASM("s_waitcnt lgkmcnt(0)");
        __builtin_amdgcn_s_setprio(1);
        acc[0][0] = __builtin_amdgcn_mfma_f32_16x16x32_bf16(a0, b0, acc[0][0], 0, 0, 0);
        acc[0][1] = __builtin_amdgcn_mfma_f32_16x16x32_bf16(a0, b1, acc[0][1], 0, 0, 0);
        acc[1][0] = __builtin_amdgcn_mfma_f32_16x16x32_bf16(a1, b0, acc[1][0], 0, 0, 0);
        acc[1][1] = __builtin_amdgcn_mfma_f32_16x16x32_bf16(a1, b1, acc[1][1], 0, 0, 0);
        acc[2][0] = __builtin_amdgcn_mfma_f32_16x16x32_bf16(a2, b0, acc[2][0], 0, 0, 0);
        acc[2][1] = __builtin_amdgcn_mfma_f32_16x16x32_bf16(a2, b1, acc[2][1], 0, 0, 0);
        acc[3][0] = __builtin_amdgcn_mfma_f32_16x16x32_bf16(a3, b0, acc[3][0], 0, 0, 0);
        acc[3][1] = __builtin_amdgcn_mfma_f32_16x16x32_bf16(a3, b1, acc[3][1], 0, 0, 0);
        __builtin_amdgcn_s_setprio(0);
        SBAR();
        // ---------- ph4: stage B1(t+2); read kk1 mq1; MFMA
        if (ds) { GLDS16(srcB[1], &smem[bufW + ldsB[1]]); srcB[1] += 64; }
        a0 = *(const short8*)&bp[offA[1][4]];
        a1 = *(const short8*)&bp[offA[1][5]];
        a2 = *(const short8*)&bp[offA[1][6]];
        a3 = *(const short8*)&bp[offA[1][7]];
        SBAR();
        WAITASM("s_waitcnt lgkmcnt(0)");
        __builtin_amdgcn_s_setprio(1);
        acc[4][0] = __builtin_amdgcn_mfma_f32_16x16x32_bf16(a0, b0, acc[4][0], 0, 0, 0);
        acc[4][1] = __builtin_amdgcn_mfma_f32_16x16x32_bf16(a0, b1, acc[4][1], 0, 0, 0);
        acc[5][0] = __builtin_amdgcn_mfma_f32_16x16x32_bf16(a1, b0, acc[5][0], 0, 0, 0);
        acc[5][1] = __builtin_amdgcn_mfma_f32_16x16x32_bf16(a1, b1, acc[5][1], 0, 0, 0);
        acc[6][0] = __builtin_amdgcn_mfma_f32_16x16x32_bf16(a2, b0, acc[6][0], 0, 0, 0);
        acc[6][1] = __builtin_amdgcn_mfma_f32_16x16x32_bf16(a2, b1, acc[6][1], 0, 0, 0);
        acc[7][0] = __builtin_amdgcn_mfma_f32_16x16x32_bf16(a3, b0, acc[7][0], 0, 0, 0);
        acc[7][1] = __builtin_amdgcn_mfma_f32_16x16x32_bf16(a3, b1, acc[7][1], 0, 0, 0);
        __builtin_amdgcn_s_setprio(0);
        SBAR();
        bufR += 24576; if (bufR == 73728) bufR = 0;
        bufW += 24576; if (bufW == 73728) bufW = 0;
    }

    // ---- epilogue
    int gRow = (lane >> 4) * 4;
    int cLane = lane & 15;
#pragma unroll
    for (int m = 0; m < 8; m++) {
#pragma unroll
        for (int j = 0; j < 4; j++) {
            int rr = m0 + wr * 128 + m * 16 + gRow + j;
            if (rr < M) {
                if (EPI == 0) {
#pragma unroll
                    for (int n = 0; n < 2; n++) {
                        int c = n0 + wc * 32 + n * 16 + cLane;
                        float v = acc[m][n][j];
                        float sv = v / (1.f + __expf(-v));
                        hs[(size_t)(baseRow + rr) * ldH + c] = f2bf(sv);
                    }
                } else {
                    int token = tok[baseRow + rr];
                    float w = gwArr[baseRow + rr];
#pragma unroll
                    for (int n = 0; n < 2; n++) {
                        int c = n0 + wc * 32 + n * 16 + cLane;
                        atomicAdd(&out[(size_t)token * C_DIM + c], w * acc[m][n][j]);
                    }
                }
            }
        }
    }
}

extern "C" void kernel_launch(void* const* d_in, const int* in_sizes, int n_in,
                              void* d_out, int out_size, void* d_ws, size_t ws_size,
                              hipStream_t stream) {
    const float* x = (const float*)d_in[0];
    const float* W1 = (const float*)d_in[1];
    const float* W2 = (const float*)d_in[2];
    const float* Wr = (const float*)d_in[3];
    float* out = (float*)d_out;

    char* p = (char*)d_ws;
    auto alloc = [&](size_t bytes) {
        char* r = p;
        p += (bytes + 255) & ~(size_t)255;
        return r;
    };
    float* pi = (float*)alloc(8 * sizeof(float));
    int* cntA = (int*)alloc(8 * sizeof(int));
    int* cursor = (int*)alloc(8 * sizeof(int));
    int* offA = (int*)alloc(8 * sizeof(int));
    int2* idx2 = (int2*)alloc((size_t)N_TOK * sizeof(int2));
    float2* wgt2 = (float2*)alloc((size_t)N_TOK * sizeof(float2));
    int* tok = (int*)alloc((size_t)N_ASSIGN * sizeof(int));
    float* gwA = (float*)alloc((size_t)N_ASSIGN * sizeof(float));
    unsigned short* W1bT = (unsigned short*)alloc((size_t)N_EXP * C_DIM * H_DIM * 2);
    unsigned short* W2bT = (unsigned short*)alloc((size_t)N_EXP * C_DIM * H_DIM * 2);
    unsigned short* xg = (unsigned short*)alloc((size_t)N_ASSIGN * C_DIM * 2);
    size_t used = (size_t)(p - (char*)d_ws);
    size_t remain = ws_size > used ? ws_size - used : 0;
    int HC = H_DIM;
    while (HC > 768 && (size_t)N_ASSIGN * HC * 2 > remain) HC >>= 1;
    unsigned short* hs = (unsigned short*)p;

    hipMemsetAsync(d_ws, 0, 1024, stream);                                      // pi, cnt, cursor, off
    hipMemsetAsync(d_out, 0, (size_t)N_TOK * C_DIM * sizeof(float), stream);    // accumulated output

    transpose_bf16_kernel<<<dim3(H_DIM / 64, C_DIM / 64, N_EXP), 256, 0, stream>>>(W1, W1bT, C_DIM, H_DIM);
    transpose_bf16_kernel<<<dim3(C_DIM / 64, H_DIM / 64, N_EXP), 256, 0, stream>>>(W2, W2bT, H_DIM, C_DIM);

    router_kernel<<<256, 256, 0, stream>>>(x, Wr, idx2, wgt2, pi, cntA);
    finalize_router_kernel<<<1, 64, 0, stream>>>(cntA, pi, offA, out + (size_t)N_TOK * C_DIM);
    scatter_kernel<<<N_ASSIGN / 256, 256, 0, stream>>>(idx2, wgt2, offA, cursor, tok, gwA);
    gather_kernel<<<N_ASSIGN / 4, 256, 0, stream>>>(x, tok, xg);

    // max logical blocks: sum_e ceil(M_e/256) <= 71. BN=128: GEMM1 ny = HC/128;
    // GEMM2 ny = 8, split-K=2. +8 physical pad for the remap bijection.
    int nChunks = H_DIM / HC;
    for (int ci = 0; ci < nChunks; ++ci) {
        int h0 = ci * HC;
        int ny1 = HC / 128;
        int sk2 = (HC >= 1536) ? 2 : 1;   // Kseg multiple of 64
        // GEMM1: [M_e x C] @ W1^T[H x C] -> silu -> hs[. x HC]; K=1024
        moe_gemm_kernel<0><<<dim3(71 * ny1 + 8, 1, 1), 512, 0, stream>>>(
            xg, C_DIM, W1bT, C_DIM, h0, 0, C_DIM, ny1, 1,
            cntA, offA, tok, gwA, hs, HC, out);
        // GEMM2: [M_e x HC] @ W2^T[C x H] -> scaled atomic scatter; split-K
        moe_gemm_kernel<1><<<dim3(71 * 8 * sk2 + 8, 1, 1), 512, 0, stream>>>(
            hs, HC, W2bT, H_DIM, 0, h0, HC / sk2, 8, sk2,
            cntA, offA, tok, gwA, hs, HC, out);
    }
}

// Round 11
// 476.594 us; speedup vs baseline: 1.1560x; 1.1560x over previous
//
#include <hip/hip_runtime.h>
#include <stdint.h>

#define N_TOK 8192
#define C_DIM 1024
#define H_DIM 3072
#define N_EXP 8
#define N_ASSIGN (N_TOK * 2)

typedef __attribute__((ext_vector_type(8))) short short8;
typedef __attribute__((ext_vector_type(4))) float f32x4;

__device__ __forceinline__ unsigned short f2bf(float f) {
    union { float f; uint32_t u; } v; v.f = f;
    uint32_t r = (v.u + 0x7FFFu + ((v.u >> 16) & 1u)) >> 16;
    return (unsigned short)r;
}

#define GLDS16(SRC, DST) __builtin_amdgcn_global_load_lds( \
    (const __attribute__((address_space(1))) void*)(SRC),  \
    (__attribute__((address_space(3))) void*)(DST), 16, 0, 0)

#define SBAR() do { __builtin_amdgcn_sched_barrier(0); \
    __builtin_amdgcn_s_barrier();                      \
    __builtin_amdgcn_sched_barrier(0); } while (0)

#define VM_WAIT(S) do { __builtin_amdgcn_sched_barrier(0); \
    asm volatile(S ::: "memory");                          \
    __builtin_amdgcn_sched_barrier(0); } while (0)

// ---------------- fused transpose + fp32->bf16 for BOTH weight tensors.
// z<8: W1 expert z (rows=C, cols=H, x over cols, y over rows);
// z>=8: W2 expert z-8 (rows=H, cols=C, roles of x/y swapped).
__global__ __launch_bounds__(256) void transpose_both_kernel(const float* __restrict__ W1,
                                                             const float* __restrict__ W2,
                                                             unsigned short* __restrict__ o1,
                                                             unsigned short* __restrict__ o2) {
    __shared__ float tile[64][65];
    int z = blockIdx.z;
    const float* ip;
    unsigned short* op;
    int rows, cols, c0, r0;
    if (z < 8) {
        ip = W1 + (size_t)z * C_DIM * H_DIM;
        op = o1 + (size_t)z * C_DIM * H_DIM;
        rows = C_DIM; cols = H_DIM;
        c0 = blockIdx.x * 64; r0 = blockIdx.y * 64;
    } else {
        ip = W2 + (size_t)(z - 8) * C_DIM * H_DIM;
        op = o2 + (size_t)(z - 8) * C_DIM * H_DIM;
        rows = H_DIM; cols = C_DIM;
        c0 = blockIdx.y * 64; r0 = blockIdx.x * 64;
    }
    int t = threadIdx.x;
    int lr = t >> 4, lc4 = t & 15;
#pragma unroll
    for (int it = 0; it < 4; it++) {
        int r = lr + it * 16;
        float4 v = *(const float4*)&ip[(size_t)(r0 + r) * cols + c0 + lc4 * 4];
        tile[lc4 * 4 + 0][r] = v.x;
        tile[lc4 * 4 + 1][r] = v.y;
        tile[lc4 * 4 + 2][r] = v.z;
        tile[lc4 * 4 + 3][r] = v.w;
    }
    __syncthreads();
#pragma unroll
    for (int it = 0; it < 4; it++) {
        int oc = lr + it * 16;
        ushort4 o;
        o.x = f2bf(tile[oc][lc4 * 4 + 0]);
        o.y = f2bf(tile[oc][lc4 * 4 + 1]);
        o.z = f2bf(tile[oc][lc4 * 4 + 2]);
        o.w = f2bf(tile[oc][lc4 * 4 + 3]);
        *(ushort4*)&op[(size_t)(c0 + oc) * rows + r0 + lc4 * 4] = o;
    }
}

// ---------------- router
__global__ __launch_bounds__(256) void router_kernel(const float* __restrict__ x, const float* __restrict__ Wr,
                                                     int2* __restrict__ idx2, float2* __restrict__ wgt2,
                                                     float* __restrict__ piAcc, int* __restrict__ cntAcc) {
    __shared__ float s_pi[8];
    __shared__ int s_cnt[8];
    int t = threadIdx.x;
    if (t < 8) { s_pi[t] = 0.f; s_cnt[t] = 0; }
    __syncthreads();
    int lane = t & 63;
    int wid = t >> 6;
    int gwv = blockIdx.x * 4 + wid;
    int nw = gridDim.x * 4;
    for (int n = gwv; n < N_TOK; n += nw) {
        float acc[8];
#pragma unroll
        for (int e = 0; e < 8; e++) acc[e] = 0.f;
        const float* xr = x + (size_t)n * C_DIM;
#pragma unroll
        for (int j = 0; j < 16; j++) {
            int k = lane + 64 * j;
            float xv = xr[k];
            const float4* wr4 = (const float4*)(Wr + (size_t)k * 8);
            float4 a = wr4[0], b = wr4[1];
            acc[0] += xv * a.x; acc[1] += xv * a.y; acc[2] += xv * a.z; acc[3] += xv * a.w;
            acc[4] += xv * b.x; acc[5] += xv * b.y; acc[6] += xv * b.z; acc[7] += xv * b.w;
        }
#pragma unroll
        for (int off = 1; off < 64; off <<= 1) {
#pragma unroll
            for (int e = 0; e < 8; e++) acc[e] += __shfl_xor(acc[e], off, 64);
        }
        float m = acc[0];
#pragma unroll
        for (int e = 1; e < 8; e++) m = fmaxf(m, acc[e]);
        float p[8]; float s = 0.f;
#pragma unroll
        for (int e = 0; e < 8; e++) { p[e] = __expf(acc[e] - m); s += p[e]; }
        float inv = 1.f / s;
#pragma unroll
        for (int e = 0; e < 8; e++) p[e] *= inv;
        int i0 = 0; float l0 = acc[0];
#pragma unroll
        for (int e = 1; e < 8; e++) if (acc[e] > l0) { l0 = acc[e]; i0 = e; }
        int i1 = -1; float l1 = -1e30f;
#pragma unroll
        for (int e = 0; e < 8; e++) if (e != i0 && acc[e] > l1) { l1 = acc[e]; i1 = e; }
        if (lane == 0) {
            float v0 = p[i0], v1 = p[i1];
            float rs = 1.f / (v0 + v1);
            idx2[n] = make_int2(i0, i1);
            wgt2[n] = make_float2(v0 * rs, v1 * rs);
            atomicAdd(&s_cnt[i0], 1);
            atomicAdd(&s_cnt[i1], 1);
#pragma unroll
            for (int e = 0; e < 8; e++) atomicAdd(&s_pi[e], p[e]);
        }
    }
    __syncthreads();
    if (t < 8) { atomicAdd(&piAcc[t], s_pi[t]); atomicAdd(&cntAcc[t], s_cnt[t]); }
}

// ---------------- offsets + aux loss
__global__ void finalize_router_kernel(const int* __restrict__ cnt, const float* __restrict__ pi,
                                       int* __restrict__ off, float* __restrict__ aux_out) {
    if (threadIdx.x == 0) {
        int o = 0;
        float dot = 0.f;
        for (int e = 0; e < 8; e++) {
            off[e] = o;
            o += cnt[e];
            dot += (float)cnt[e] * pi[e];
        }
        aux_out[0] = 0.01f * 8.f * dot / ((float)N_TOK * (float)N_TOK);
    }
}

// ---------------- scatter
__global__ __launch_bounds__(256) void scatter_kernel(const int2* __restrict__ idx2, const float2* __restrict__ wgt2,
                                                      const int* __restrict__ off, int* __restrict__ cursor,
                                                      int* __restrict__ tok, float* __restrict__ gwArr) {
    __shared__ int lcnt[8], lbase[8];
    int t = threadIdx.x;
    if (t < 8) lcnt[t] = 0;
    __syncthreads();
    int a = blockIdx.x * 256 + t;
    int n = a >> 1, k = a & 1;
    int2 id = idx2[n];
    float2 w = wgt2[n];
    int e = k ? id.y : id.x;
    float wv = k ? w.y : w.x;
    int rank = atomicAdd(&lcnt[e], 1);
    __syncthreads();
    if (t < 8) lbase[t] = atomicAdd(&cursor[t], lcnt[t]);
    __syncthreads();
    int pos = off[e] + lbase[e] + rank;
    tok[pos] = n;
    gwArr[pos] = wv;
}

// ---------------- gather
__global__ __launch_bounds__(256) void gather_kernel(const float* __restrict__ x, const int* __restrict__ tok,
                                                     unsigned short* __restrict__ xg) {
    int wid = threadIdx.x >> 6, lane = threadIdx.x & 63;
    int row = blockIdx.x * 4 + wid;
    int n = tok[row];
    const float4* src = (const float4*)(x + (size_t)n * C_DIM);
    ushort4* dst = (ushort4*)(xg + (size_t)row * C_DIM);
#pragma unroll
    for (int j = 0; j < 4; j++) {
        float4 v = src[lane + 64 * j];
        ushort4 o;
        o.x = f2bf(v.x); o.y = f2bf(v.y); o.z = f2bf(v.z); o.w = f2bf(v.w);
        dst[lane + 64 * j] = o;
    }
}

// ---------------- grouped GEMM: R7 multi-block m97 frame + BK=32 DOUBLE-BUFFER
// with counted vmcnt (removes the per-step vmcnt(0) drain; the ONLY change vs R7).
// 128x128 tile, 4 waves (2x2), LDS = 2 bufs x (A 8 KiB + B 8 KiB) = 32 KiB total
// -> same occupancy as R7 (~3 blocks/CU, VGPR-limited).
//   prologue: stage tile0 -> buf0 (4 loads/thread, FIFO A,A,B,B)
//   iter t:  stage tile t+1 -> buf[(t+1)&1] ; vmcnt(4) [last iter: 0] ; SBAR ;
//            ds_read 4a+4b from buf[t&1] ; setprio1 ; 16 MFMA ; setprio0 ; SBAR
// FIFO audit: 4 loads/thread/tile. At iter t after staging t+1: outstanding =
// t's 4 + t+1's 4 -> vmcnt(4) lands tile t; barrier makes it all-waves.
// Overwrite audit: stage t+1 hits buf[(t+1)&1], last read at iter t-1 and sealed
// by t-1's trailing SBAR (ds_reads feed MFMAs -> lgkm drained pre-barrier).
// LDS rows = 32 shorts (64 B); within-row chunk swizzle sc = pos ^ ((row>>1)&3)
// on SOURCE and READ (contiguous 1-KiB wave staging; 0 conflicts, PMC R8).
// Work: flat (e, mblk, y, s[split-K]) + bijective XCD remap (m204), mb-inner.
// EPI=0: hs = bf16(silu(acc)); EPI=1: atomicAdd(out[tok*C+c], gw*acc)
template <int EPI>
__global__ __launch_bounds__(256) void moe_gemm_kernel(
    const unsigned short* __restrict__ A, int ldA,
    const unsigned short* __restrict__ Bt, int ldB, int bRowOff, int bColOff,
    int Kseg, int NY, int SK,
    const int* __restrict__ cnt, const int* __restrict__ off,
    const int* __restrict__ tok, const float* __restrict__ gwArr,
    unsigned short* __restrict__ hs, int ldH,
    float* __restrict__ out) {
    __shared__ unsigned short As[2][4096];   // [buf][128 rows x 32 shorts] = 8 KiB each
    __shared__ unsigned short Bs[2][4096];

    // ---- flat work total + bijective XCD remap
    int nbs[8];
    int tot = 0;
#pragma unroll
    for (int i = 0; i < 8; i++) {
        nbs[i] = (cnt[i] + 127) >> 7;
        tot += nbs[i] * NY * SK;
    }
    int p = blockIdx.x;
    int q = tot >> 3, r = tot & 7;
    int xx = p & 7, sp = p >> 3;
    int capx = (xx < r) ? q + 1 : q;
    if (sp >= capx) return;
    int wi = (xx < r) ? xx * (q + 1) + sp : r * (q + 1) + (xx - r) * q + sp;

    // ---- decode wi -> (e, mblk, y, s); mb-inner for B-stripe L2 reuse
    int base = 0, e = -1, enb = 0, local = 0;
#pragma unroll
    for (int i = 0; i < 8; i++) {
        int sz = nbs[i] * NY * SK;
        if (e < 0 && wi < base + sz) { e = i; enb = nbs[i]; local = wi - base; }
        base += sz;
    }
    if (e < 0) return;
    int ys = local / enb;
    int mblk = local - ys * enb;
    int s = ys / NY;
    int y = ys - s * NY;
    int M = cnt[e];
    int m0 = mblk * 128;
    int baseRow = off[e];
    int n0 = y * 128;
    int acol = s * Kseg;
    int bcol = bColOff + s * Kseg;

    int tid = threadIdx.x;
    int lane = tid & 63;
    int wid = tid >> 6;
    int wm = (wid >> 1) * 64;
    int wn = (wid & 1) * 64;

    f32x4 acc[4][4];
#pragma unroll
    for (int i = 0; i < 4; i++)
#pragma unroll
        for (int j = 0; j < 4; j++) acc[i][j] = (f32x4)0.f;

    const unsigned short* Bex = Bt + (size_t)e * (size_t)(C_DIM * H_DIM);

    // ---- staging: per matrix tile 128 rows x 4 chunks (16B) = 512 chunks; 2/thread.
    // chunk c: row=c>>2, pos=c&3, src chunk = pos ^ ((row>>1)&3); each wave
    // instruction covers 16 consecutive rows = contiguous 1 KiB (permuted within).
    const unsigned short* srcA[2];
    const unsigned short* srcB[2];
    int ldsOff[2];
#pragma unroll
    for (int i = 0; i < 2; i++) {
        int c = i * 256 + tid;
        int row = c >> 2;
        int pos = c & 3;
        int sc = pos ^ ((row >> 1) & 3);
        int rg = m0 + row; if (rg > M - 1) rg = M - 1;
        srcA[i] = A + (size_t)(baseRow + rg) * ldA + acol + sc * 8;
        srcB[i] = Bex + (size_t)(bRowOff + n0 + row) * ldB + bcol + sc * 8;
        ldsOff[i] = (c & ~63) * 8;   // shorts; wave-uniform base + lane*16B implicit
    }

    // ---- swizzled read offsets (shorts): row rr, k-chunk kq -> kq ^ ((rr>>1)&3)
    int kq = lane >> 4;
    int rsub = lane & 15;
    int offA[4], offB[4];
#pragma unroll
    for (int m = 0; m < 4; m++) {
        int rr = wm + m * 16 + rsub;
        offA[m] = rr * 32 + ((kq ^ ((rr >> 1) & 3)) * 8);
    }
#pragma unroll
    for (int n = 0; n < 4; n++) {
        int rn = wn + n * 16 + rsub;
        offB[n] = rn * 32 + ((kq ^ ((rn >> 1) & 3)) * 8);
    }

    int nt = Kseg >> 5;
    // ---- prologue: stage tile 0 -> buf 0 (FIFO: A0,A1,B0,B1)
#pragma unroll
    for (int i = 0; i < 2; i++) GLDS16(srcA[i], &As[0][ldsOff[i]]);
#pragma unroll
    for (int i = 0; i < 2; i++) GLDS16(srcB[i], &Bs[0][ldsOff[i]]);
#pragma unroll
    for (int i = 0; i < 2; i++) { srcA[i] += 32; srcB[i] += 32; }

#pragma unroll 1
    for (int t = 0; t < nt; ++t) {
        if (t + 1 < nt) {
            int nb = (t + 1) & 1;
#pragma unroll
            for (int i = 0; i < 2; i++) GLDS16(srcA[i], &As[nb][ldsOff[i]]);
#pragma unroll
            for (int i = 0; i < 2; i++) GLDS16(srcB[i], &Bs[nb][ldsOff[i]]);
#pragma unroll
            for (int i = 0; i < 2; i++) { srcA[i] += 32; srcB[i] += 32; }
            VM_WAIT("s_waitcnt vmcnt(4)");
        } else {
            VM_WAIT("s_waitcnt vmcnt(0)");
        }
        SBAR();
        int cb = t & 1;
        short8 a[4], b[4];
#pragma unroll
        for (int m = 0; m < 4; m++) a[m] = *(const short8*)&As[cb][offA[m]];
#pragma unroll
        for (int n = 0; n < 4; n++) b[n] = *(const short8*)&Bs[cb][offB[n]];
        __builtin_amdgcn_s_setprio(1);
#pragma unroll
        for (int m = 0; m < 4; m++)
#pragma unroll
            for (int n = 0; n < 4; n++)
                acc[m][n] = __builtin_amdgcn_mfma_f32_16x16x32_bf16(a[m], b[n], acc[m][n], 0, 0, 0);
        __builtin_amdgcn_s_setprio(0);
        SBAR();
    }

    // ---- epilogue
    int gRow = (lane >> 4) * 4;
    int cLane = lane & 15;
#pragma unroll
    for (int m = 0; m < 4; m++) {
#pragma unroll
        for (int j = 0; j < 4; j++) {
            int rr = m0 + wm + m * 16 + gRow + j;
            if (rr < M) {
                if (EPI == 0) {
#pragma unroll
                    for (int n = 0; n < 4; n++) {
                        int c = n0 + wn + n * 16 + cLane;
                        float v = acc[m][n][j];
                        float sv = v / (1.f + __expf(-v));
                        hs[(size_t)(baseRow + rr) * ldH + c] = f2bf(sv);
                    }
                } else {
                    int token = tok[baseRow + rr];
                    float w = gwArr[baseRow + rr];
#pragma unroll
                    for (int n = 0; n < 4; n++) {
                        int c = n0 + wn + n * 16 + cLane;
                        atomicAdd(&out[(size_t)token * C_DIM + c], w * acc[m][n][j]);
                    }
                }
            }
        }
    }
}

extern "C" void kernel_launch(void* const* d_in, const int* in_sizes, int n_in,
                              void* d_out, int out_size, void* d_ws, size_t ws_size,
                              hipStream_t stream) {
    const float* x = (const float*)d_in[0];
    const float* W1 = (const float*)d_in[1];
    const float* W2 = (const float*)d_in[2];
    const float* Wr = (const float*)d_in[3];
    float* out = (float*)d_out;

    char* p = (char*)d_ws;
    auto alloc = [&](size_t bytes) {
        char* r = p;
        p += (bytes + 255) & ~(size_t)255;
        return r;
    };
    float* pi = (float*)alloc(8 * sizeof(float));
    int* cntA = (int*)alloc(8 * sizeof(int));
    int* cursor = (int*)alloc(8 * sizeof(int));
    int* offA = (int*)alloc(8 * sizeof(int));
    int2* idx2 = (int2*)alloc((size_t)N_TOK * sizeof(int2));
    float2* wgt2 = (float2*)alloc((size_t)N_TOK * sizeof(float2));
    int* tok = (int*)alloc((size_t)N_ASSIGN * sizeof(int));
    float* gwA = (float*)alloc((size_t)N_ASSIGN * sizeof(float));
    unsigned short* W1bT = (unsigned short*)alloc((size_t)N_EXP * C_DIM * H_DIM * 2);
    unsigned short* W2bT = (unsigned short*)alloc((size_t)N_EXP * C_DIM * H_DIM * 2);
    unsigned short* xg = (unsigned short*)alloc((size_t)N_ASSIGN * C_DIM * 2);
    size_t used = (size_t)(p - (char*)d_ws);
    size_t remain = ws_size > used ? ws_size - used : 0;
    int HC = H_DIM;
    while (HC > 384 && (size_t)N_ASSIGN * HC * 2 > remain) HC >>= 1;
    unsigned short* hs = (unsigned short*)p;

    hipMemsetAsync(d_ws, 0, 1024, stream);                                      // pi, cnt, cursor, off
    hipMemsetAsync(d_out, 0, (size_t)N_TOK * C_DIM * sizeof(float), stream);    // accumulated output

    transpose_both_kernel<<<dim3(48, 16, 16), 256, 0, stream>>>(W1, W2, W1bT, W2bT);

    router_kernel<<<256, 256, 0, stream>>>(x, Wr, idx2, wgt2, pi, cntA);
    finalize_router_kernel<<<1, 64, 0, stream>>>(cntA, pi, offA, out + (size_t)N_TOK * C_DIM);
    scatter_kernel<<<N_ASSIGN / 256, 256, 0, stream>>>(idx2, wgt2, offA, cursor, tok, gwA);
    gather_kernel<<<N_ASSIGN / 4, 256, 0, stream>>>(x, tok, xg);

    // max non-empty logical blocks: sum_e ceil(M_e/128) <= 16384/128 + 7 = 135
    int nChunks = H_DIM / HC;
    for (int ci = 0; ci < nChunks; ++ci) {
        int h0 = ci * HC;
        int ny1 = HC / 128;
        int sk2 = (HC >= 1536) ? 2 : 1;   // Kseg = HC/sk2, multiple of 32
        // GEMM1: [M_e x C] @ W1^T[H x C] -> silu -> hs[. x HC]; K=1024
        moe_gemm_kernel<0><<<dim3(135 * ny1 + 8, 1, 1), 256, 0, stream>>>(
            xg, C_DIM, W1bT, C_DIM, h0, 0, C_DIM, ny1, 1,
            cntA, offA, tok, gwA, hs, HC, out);
        // GEMM2: [M_e x HC] @ W2^T[C x H] -> scaled atomic scatter; split-K
        moe_gemm_kernel<1><<<dim3(135 * 8 * sk2 + 8, 1, 1), 256, 0, stream>>>(
            hs, HC, W2bT, H_DIM, 0, h0, HC / sk2, 8, sk2,
            cntA, offA, tok, gwA, hs, HC, out);
    }
}